// Round 1
// baseline (194.128 us; speedup 1.0000x reference)
//
#include <hip/hip_runtime.h>
#include <math.h>

#define BB 2
#define KK 3
#define NN 2048
#define TT 256
#define CH 8
#define CG_IT 30
#define CG_TOL_D 1e-6

#define PI_D 3.14159265358979323846
#define TWO_PI_D (2.0 * PI_D)

// ---- workspace layout (in doubles) ----
#define WS_SCAL 0                       // [0]=new_alpha [1]=new_beta [2]=betathr
#define WS_U    8
#define WS_COS  (WS_U + BB*NN)
#define WS_SIN  (WS_COS + BB*KK*NN)
#define WS_BX   (WS_SIN + BB*KK*NN)
#define WS_BY   (WS_BX + BB*KK*NN)
#define WS_SOLX (WS_BY + BB*KK*NN)
#define WS_SOLY (WS_SOLX + BB*KK*NN)
#define WS_DEL  (WS_SOLY + BB*KK*NN)
#define WS_DSM  (WS_DEL + BB*KK*NN)
#define WS_CX   (WS_DSM + BB*KK*NN)
#define WS_CY   (WS_CX + BB*KK*NN)
#define WS_TOTAL (WS_CY + BB*KK*NN)

// ---- output layout (floats) ----
#define OUT_EIF 0
#define OUT_XM  (BB*KK*NN)
#define OUT_YM  (2*BB*KK*NN)
#define OUT_SX  (3*BB*KK*NN)
#define OUT_SY  (3*BB*KK*NN + BB*NN)
#define OUT_LM  (3*BB*KK*NN + 2*BB*NN)
#define OUT_A   (3*BB*KK*NN + 3*BB*NN)
#define OUT_B2  (OUT_A + 1)

// block-wide sum of doubles; deterministic (all lanes compute same final sum)
__device__ __forceinline__ double blk_reduce(double v, double* sred) {
    #pragma unroll
    for (int o = 32; o > 0; o >>= 1) v += __shfl_down(v, o, 64);
    const int wid = threadIdx.x >> 6;
    const int lid = threadIdx.x & 63;
    __syncthreads();               // protect sred vs. previous call's readers
    if (lid == 0) sred[wid] = v;
    __syncthreads();
    return sred[0] + sred[1] + sred[2] + sred[3];
}

// T (tridiagonal: diag -1 at ends / -2 interior, off-diag +1) applied at index i
__device__ __forceinline__ double Tap(const double* a, int i) {
    double d = (i == 0 || i == NN - 1) ? -1.0 : -2.0;
    double t = d * a[i];
    if (i > 0) t += a[i - 1];
    if (i < NN - 1) t += a[i + 1];
    return t;
}

// CG solve of (c*T^2 + diag(dg)) x = b ; dg includes the +1e-6 regularization.
// Per-thread arrays are CH long (thread owns elements [tid*CH, tid*CH+CH)).
__device__ void cg_solve(double c, const double* dg, const double* bv, const double* x0v,
                         double* xr, double* shP, double* shT, double* sred) {
    const int tid = threadIdx.x;
    const int i0 = tid * CH;
    double r[CH], ap[CH], pl[CH];

    #pragma unroll
    for (int j = 0; j < CH; ++j) { xr[j] = x0v[j]; shP[i0 + j] = x0v[j]; }
    __syncthreads();
    #pragma unroll
    for (int j = 0; j < CH; ++j) shT[i0 + j] = Tap(shP, i0 + j);
    __syncthreads();
    double rs = 0.0;
    #pragma unroll
    for (int j = 0; j < CH; ++j) {
        double ax = c * Tap(shT, i0 + j) + dg[j] * xr[j];
        r[j] = bv[j] - ax;
        rs += r[j] * r[j];
    }
    #pragma unroll
    for (int j = 0; j < CH; ++j) shP[i0 + j] = r[j];   // p = r
    double rsold = blk_reduce(rs, sred);               // leading barrier publishes shP

    for (int it = 0; it < CG_IT; ++it) {
        #pragma unroll
        for (int j = 0; j < CH; ++j) pl[j] = shP[i0 + j];
        #pragma unroll
        for (int j = 0; j < CH; ++j) shT[i0 + j] = Tap(shP, i0 + j);
        __syncthreads();
        double pap = 0.0;
        #pragma unroll
        for (int j = 0; j < CH; ++j) {
            ap[j] = c * Tap(shT, i0 + j) + dg[j] * pl[j];
            pap += pl[j] * ap[j];
        }
        pap = blk_reduce(pap, sred);
        double a = rsold / (pap + 1e-12);
        double rs2 = 0.0;
        #pragma unroll
        for (int j = 0; j < CH; ++j) {
            xr[j] += a * pl[j];
            r[j]  -= a * ap[j];
            rs2 += r[j] * r[j];
        }
        double rsnew = blk_reduce(rs2, sred);
        if (sqrt(rsnew) < CG_TOL_D) break;   // uniform; matches reference freeze
        double bta = rsnew / (rsold + 1e-12);
        #pragma unroll
        for (int j = 0; j < CH; ++j) shP[i0 + j] = r[j] + bta * pl[j];
        rsold = rsnew;
        __syncthreads();                     // publish new p for next iteration
    }
}

// ---------------- kernel 1: per-mode stats + hyperparameter MLPs ----------------
__global__ void stats_mlp_kernel(const float* eIF, const float* alpha_p, const float* beta_p,
                                 const float* fe_w1, const float* fe_b1,
                                 const float* fe_w2, const float* fe_b2,
                                 const float* pr_w1, const float* pr_b1,
                                 const float* pr_w2, const float* pr_b2,
                                 const float* pr_w3, const float* pr_b3,
                                 const float* iter_w_p, const int* mode_mask,
                                 const int* iter_p, double* wsd, float* out) {
    __shared__ double sred[4];
    __shared__ double feats[BB][KK][2];
    __shared__ double inF[BB][2];
    __shared__ double h1[BB][32];
    __shared__ double cbuf[BB][18];
    __shared__ double r1[BB][64];
    __shared__ double r2b[BB][32];
    __shared__ double resb[BB][2];
    const int tid = threadIdx.x;

    for (int p = 0; p < BB * KK; ++p) {
        double sum = 0.0, sq = 0.0;
        for (int i = tid; i < NN - 1; i += TT) {
            double d = (double)eIF[p * NN + i + 1] - (double)eIF[p * NN + i];
            sum += d; sq += d * d;
        }
        double S = blk_reduce(sum, sred);
        double Q = blk_reduce(sq, sred);
        if (tid == 0) {
            const double nd = (double)(NN - 1);
            double m = S / nd;
            double v = (Q - nd * m * m) / (nd - 1.0);   // ddof=1
            bool mk = mode_mask[p] > 0;
            feats[p / KK][p % KK][0] = mk ? m : 0.0;
            feats[p / KK][p % KK][1] = mk ? v : 0.0;
        }
    }
    __syncthreads();
    if (tid < BB * 2) {
        int b = tid / 2, j = tid % 2;
        double sv = 0.0;
        for (int k = 0; k < KK; ++k) sv += feats[b][k][j];
        inF[b][j] = sv / (double)KK;
    }
    __syncthreads();
    if (tid < BB * 32) {
        int b = tid / 32, o = tid % 32;
        double a = (double)fe_b1[o];
        for (int j = 0; j < 2; ++j) a += inF[b][j] * (double)fe_w1[o * 2 + j];
        h1[b][o] = fmax(a, 0.0);
    }
    __syncthreads();
    if (tid < BB * 16) {
        int b = tid / 16, o = tid % 16;
        double a = (double)fe_b2[o];
        for (int j = 0; j < 32; ++j) a += h1[b][j] * (double)fe_w2[o * 32 + j];
        cbuf[b][o] = fmax(a, 0.0);
    }
    if (tid < BB) {
        cbuf[tid][16] = (double)alpha_p[0];
        cbuf[tid][17] = (double)beta_p[0];
    }
    __syncthreads();
    if (tid < BB * 64) {
        int b = tid / 64, o = tid % 64;
        double a = (double)pr_b1[o];
        for (int j = 0; j < 18; ++j) a += cbuf[b][j] * (double)pr_w1[o * 18 + j];
        r1[b][o] = fmax(a, 0.0);
    }
    __syncthreads();
    if (tid < BB * 32) {
        int b = tid / 32, o = tid % 32;
        double a = (double)pr_b2[o];
        for (int j = 0; j < 64; ++j) a += r1[b][j] * (double)pr_w2[o * 64 + j];
        r2b[b][o] = fmax(a, 0.0);
    }
    __syncthreads();
    if (tid < BB * 2) {
        int b = tid / 2, o = tid % 2;
        double a = (double)pr_b3[o];
        for (int j = 0; j < 32; ++j) a += r2b[b][j] * (double)pr_w3[o * 32 + j];
        double t = tanh(a);
        double sg = 1.0 / (1.0 + exp(-(double)iter_w_p[0] * (double)iter_p[0]));
        resb[b][o] = t * sg * 0.1;
    }
    __syncthreads();
    if (tid == 0) {
        double al = (double)alpha_p[0], be = (double)beta_p[0];
        double ma = 0.0, mb = 0.0;
        for (int b = 0; b < BB; ++b) { ma += resb[b][0] * al; mb += resb[b][1] * be; }
        ma /= (double)BB; mb /= (double)BB;
        double na = fmin(fmax(al + ma, 1e-6), 0.01);
        double nb = fmin(fmax(be + mb, 1e-6), 0.1);
        float thr32 = (float)pow(10.0, (double)iter_p[0] / 36.0 - 10.0);
        double bt = fmin((double)thr32, nb);
        wsd[0] = na; wsd[1] = nb; wsd[2] = bt;
        out[OUT_A]  = (float)na;
        out[OUT_B2] = (float)nb;
    }
}

// ---------------- kernel 2: projection u ----------------
__global__ void u_kernel(const float* s, const float* sum_x, const float* sum_y,
                         const float* lamuda, const float* var_p, double* wsd) {
    __shared__ double sred[4];
    const int b = blockIdx.x;
    const int tid = threadIdx.x;
    const int i0 = tid * CH;
    const double na = wsd[0];
    const double var = (double)var_p[0];
    double* u = wsd + WS_U + (size_t)b * NN;
    double dv[CH];
    double loc = 0.0;
    #pragma unroll
    for (int j = 0; j < CH; ++j) {
        int i = i0 + j;
        double d = (double)s[b * NN + i] - (double)sum_x[b * NN + i]
                 - (double)sum_y[b * NN + i] - (double)lamuda[b * NN + i] / na;
        dv[j] = d; loc += d * d;
    }
    double nrm2 = blk_reduce(loc, sred);
    double e = sqrt((double)NN * var);
    double nrm = sqrt(nrm2);
    double scale = (var <= 0.0) ? 0.0 : ((nrm > e) ? e / nrm : 1.0);
    #pragma unroll
    for (int j = 0; j < CH; ++j) u[i0 + j] = dv[j] * scale;
}

// ---------------- kernel 3: phase scan + cos/sin + rhs ----------------
__global__ void prep_kernel(const float* s, const float* eIF, const float* xm, const float* ym,
                            const float* sum_x, const float* sum_y, const float* lamuda,
                            const float* fs_p, double* wsd) {
    __shared__ double tot[TT];
    const int bk = blockIdx.x;
    const int b = bk / KK;
    const int tid = threadIdx.x;
    const int i0 = tid * CH;
    const double dx = 1.0 / (double)fs_p[0];
    const float* E = eIF + (size_t)bk * NN;

    double run = 0.0, ph[CH];
    double eprev = (i0 > 0) ? (double)E[i0 - 1] : 0.0;
    #pragma unroll
    for (int j = 0; j < CH; ++j) {
        double ec = (double)E[i0 + j];
        double inc = (i0 + j == 0) ? 0.0 : 0.5 * (eprev + ec) * dx;
        run += inc; ph[j] = run; eprev = ec;
    }
    tot[tid] = run;
    __syncthreads();
    for (int sft = 1; sft < TT; sft <<= 1) {
        double v = (tid >= sft) ? tot[tid - sft] : 0.0;
        __syncthreads();
        tot[tid] += v;
        __syncthreads();
    }
    double excl = (tid > 0) ? tot[tid - 1] : 0.0;

    const double na = wsd[0];
    const double* u = wsd + WS_U + (size_t)b * NN;
    double* cosm = wsd + WS_COS + (size_t)bk * NN;
    double* sinm = wsd + WS_SIN + (size_t)bk * NN;
    double* bx = wsd + WS_BX + (size_t)bk * NN;
    double* by = wsd + WS_BY + (size_t)bk * NN;
    #pragma unroll
    for (int j = 0; j < CH; ++j) {
        int i = i0 + j;
        double phase = TWO_PI_D * (excl + ph[j]);
        double cs = cos(phase), sn = sin(phase);
        cosm[i] = cs; sinm[i] = sn;
        double rhs = (double)s[b * NN + i]
                   - ((double)sum_x[b * NN + i] - (double)xm[bk * NN + i] * cs)
                   - ((double)sum_y[b * NN + i] - (double)ym[bk * NN + i] * sn)
                   - u[i] - (double)lamuda[b * NN + i] / na;
        bx[i] = cs * rhs; by[i] = sn * rhs;
    }
}

// ---------------- kernel 4: CG solves for x and y ----------------
__global__ void cg_xy_kernel(const float* xm, const float* ym, double* wsd) {
    __shared__ double shP[NN];
    __shared__ double shT[NN];
    __shared__ double sred[4];
    const int idx = blockIdx.x;
    const int which = idx & 1;     // 0 = x-solve, 1 = y-solve
    const int bk = idx >> 1;
    const int tid = threadIdx.x;
    const int i0 = tid * CH;
    const double c = 2.0 / wsd[0];
    const double* trig = wsd + (which ? WS_SIN : WS_COS) + (size_t)bk * NN;
    const double* bg   = wsd + (which ? WS_BY  : WS_BX ) + (size_t)bk * NN;
    const float*  x0g  = (which ? ym : xm) + (size_t)bk * NN;
    double* outg = wsd + (which ? WS_SOLY : WS_SOLX) + (size_t)bk * NN;

    double dg[CH], bv[CH], x0v[CH], xr[CH];
    #pragma unroll
    for (int j = 0; j < CH; ++j) {
        double t = trig[i0 + j];
        dg[j] = t * t + 1e-6;
        bv[j] = bg[i0 + j];
        x0v[j] = (double)x0g[i0 + j];
    }
    cg_solve(c, dg, bv, x0v, xr, shP, shT, sred);
    #pragma unroll
    for (int j = 0; j < CH; ++j) outg[i0 + j] = xr[j];
}

// ---------------- kernel 5: deltaIF via differ5 ----------------
__global__ void delta_kernel(const float* fs_p, double* wsd) {
    const int bk = blockIdx.x;
    const int tid = threadIdx.x;
    const int i0 = tid * CH;
    const double dlt = 1.0 / (double)fs_p[0];
    const double* X = wsd + WS_SOLX + (size_t)bk * NN;
    const double* Y = wsd + WS_SOLY + (size_t)bk * NN;
    double* D = wsd + WS_DEL + (size_t)bk * NN;
    #pragma unroll
    for (int j = 0; j < CH; ++j) {
        int i = i0 + j;
        double xb, yb;
        if (i == 0)            { xb = (X[1] - X[0]) / dlt;          yb = (Y[1] - Y[0]) / dlt; }
        else if (i == NN - 1)  { xb = (X[NN-1] - X[NN-2]) / dlt;    yb = (Y[NN-1] - Y[NN-2]) / dlt; }
        else                   { xb = (X[i+1] - X[i-1]) / (2.0*dlt); yb = (Y[i+1] - Y[i-1]) / (2.0*dlt); }
        D[i] = (X[i] * yb - Y[i] * xb) / ((X[i] * X[i] + Y[i] * Y[i] + 1e-12) * 2.0 * PI_D);
    }
}

// ---------------- kernel 6: smoothing CG solve ----------------
__global__ void cg_s_kernel(double* wsd) {
    __shared__ double shP[NN];
    __shared__ double shT[NN];
    __shared__ double sred[4];
    const int bk = blockIdx.x;
    const int tid = threadIdx.x;
    const int i0 = tid * CH;
    const double c = 2.0 / wsd[2];   // 2 / betathr
    const double* bg = wsd + WS_DEL + (size_t)bk * NN;
    double* outg = wsd + WS_DSM + (size_t)bk * NN;

    double dg[CH], bv[CH], x0v[CH], xr[CH];
    #pragma unroll
    for (int j = 0; j < CH; ++j) {
        dg[j] = 1.0 + 1e-6;          // identity + regularization
        bv[j] = bg[i0 + j];
        x0v[j] = 0.0;
    }
    cg_solve(c, dg, bv, x0v, xr, shP, shT, sred);
    #pragma unroll
    for (int j = 0; j < CH; ++j) outg[i0 + j] = xr[j];
}

// ---------------- kernel 7: new phase scan + per-mode outputs ----------------
__global__ void final_kernel(const float* eIF, const float* xm, const float* ym,
                             const int* mode_mask, const float* fs_p,
                             double* wsd, float* out) {
    __shared__ double tot[TT];
    const int bk = blockIdx.x;
    const int tid = threadIdx.x;
    const int i0 = tid * CH;
    const double dx = 1.0 / (double)fs_p[0];
    const bool mk = mode_mask[bk] > 0;
    const double* dsm = wsd + WS_DSM + (size_t)bk * NN;
    const double* SX = wsd + WS_SOLX + (size_t)bk * NN;
    const double* SY = wsd + WS_SOLY + (size_t)bk * NN;
    double* cxm = wsd + WS_CX + (size_t)bk * NN;
    double* cym = wsd + WS_CY + (size_t)bk * NN;

    double run = 0.0, ph[CH], nev[CH];
    double eprev = (i0 > 0)
        ? ((double)eIF[bk * NN + i0 - 1] - 0.5 * dsm[i0 - 1]) : 0.0;
    #pragma unroll
    for (int j = 0; j < CH; ++j) {
        int i = i0 + j;
        double ec = (double)eIF[bk * NN + i] - 0.5 * dsm[i];
        nev[j] = ec;
        double inc = (i == 0) ? 0.0 : 0.5 * (eprev + ec) * dx;
        run += inc; ph[j] = run; eprev = ec;
    }
    tot[tid] = run;
    __syncthreads();
    for (int sft = 1; sft < TT; sft <<= 1) {
        double v = (tid >= sft) ? tot[tid - sft] : 0.0;
        __syncthreads();
        tot[tid] += v;
        __syncthreads();
    }
    double excl = (tid > 0) ? tot[tid - 1] : 0.0;
    #pragma unroll
    for (int j = 0; j < CH; ++j) {
        int i = i0 + j;
        double nph = TWO_PI_D * (excl + ph[j]);
        double cxv = SX[i] * cos(nph);
        double cyv = SY[i] * sin(nph);
        out[OUT_EIF + bk * NN + i] = mk ? (float)nev[j] : eIF[bk * NN + i];
        out[OUT_XM  + bk * NN + i] = mk ? (float)SX[i]  : xm[bk * NN + i];
        out[OUT_YM  + bk * NN + i] = mk ? (float)SY[i]  : ym[bk * NN + i];
        cxm[i] = mk ? cxv : 0.0;
        cym[i] = mk ? cyv : 0.0;
    }
}

// ---------------- kernel 8: k-sum + lamuda update ----------------
__global__ void sum_kernel(const float* s, const float* lamuda, const double* wsd, float* out) {
    const int b = blockIdx.x;
    const int tid = threadIdx.x;
    const int i0 = tid * CH;
    const double na = wsd[0];
    const double* u = wsd + WS_U + (size_t)b * NN;
    #pragma unroll
    for (int j = 0; j < CH; ++j) {
        int i = i0 + j;
        double nsx = 0.0, nsy = 0.0;
        for (int k = 0; k < KK; ++k) {
            nsx += wsd[WS_CX + (size_t)(b * KK + k) * NN + i];
            nsy += wsd[WS_CY + (size_t)(b * KK + k) * NN + i];
        }
        out[OUT_SX + b * NN + i] = (float)nsx;
        out[OUT_SY + b * NN + i] = (float)nsy;
        out[OUT_LM + b * NN + i] =
            (float)((double)lamuda[b * NN + i] + na * (u[i] + nsx + nsy - (double)s[b * NN + i]));
    }
}

extern "C" void kernel_launch(void* const* d_in, const int* in_sizes, int n_in,
                              void* d_out, int out_size, void* d_ws, size_t ws_size,
                              hipStream_t stream) {
    const float* s      = (const float*)d_in[0];
    const float* eIF    = (const float*)d_in[1];
    const float* xm     = (const float*)d_in[2];
    const float* ym     = (const float*)d_in[3];
    const float* sum_x  = (const float*)d_in[4];
    const float* sum_y  = (const float*)d_in[5];
    const float* lamuda = (const float*)d_in[6];
    const float* alpha  = (const float*)d_in[7];
    const float* beta   = (const float*)d_in[8];
    const float* fe_w1  = (const float*)d_in[9];
    const float* fe_b1  = (const float*)d_in[10];
    const float* fe_w2  = (const float*)d_in[11];
    const float* fe_b2  = (const float*)d_in[12];
    const float* pr_w1  = (const float*)d_in[13];
    const float* pr_b1  = (const float*)d_in[14];
    const float* pr_w2  = (const float*)d_in[15];
    const float* pr_b2  = (const float*)d_in[16];
    const float* pr_w3  = (const float*)d_in[17];
    const float* pr_b3  = (const float*)d_in[18];
    const float* iter_w = (const float*)d_in[19];
    const int*   mode_mask = (const int*)d_in[20];
    const float* var    = (const float*)d_in[21];
    const float* fs     = (const float*)d_in[22];
    const int*   iteration = (const int*)d_in[23];
    float* out = (float*)d_out;
    double* wsd = (double*)d_ws;

    if (ws_size < (size_t)WS_TOTAL * sizeof(double)) return;  // ~1.02 MB needed

    hipLaunchKernelGGL(stats_mlp_kernel, dim3(1), dim3(TT), 0, stream,
                       eIF, alpha, beta, fe_w1, fe_b1, fe_w2, fe_b2,
                       pr_w1, pr_b1, pr_w2, pr_b2, pr_w3, pr_b3,
                       iter_w, mode_mask, iteration, wsd, out);
    hipLaunchKernelGGL(u_kernel, dim3(BB), dim3(TT), 0, stream,
                       s, sum_x, sum_y, lamuda, var, wsd);
    hipLaunchKernelGGL(prep_kernel, dim3(BB * KK), dim3(TT), 0, stream,
                       s, eIF, xm, ym, sum_x, sum_y, lamuda, fs, wsd);
    hipLaunchKernelGGL(cg_xy_kernel, dim3(BB * KK * 2), dim3(TT), 0, stream,
                       xm, ym, wsd);
    hipLaunchKernelGGL(delta_kernel, dim3(BB * KK), dim3(TT), 0, stream,
                       fs, wsd);
    hipLaunchKernelGGL(cg_s_kernel, dim3(BB * KK), dim3(TT), 0, stream,
                       wsd);
    hipLaunchKernelGGL(final_kernel, dim3(BB * KK), dim3(TT), 0, stream,
                       eIF, xm, ym, mode_mask, fs, wsd, out);
    hipLaunchKernelGGL(sum_kernel, dim3(BB), dim3(TT), 0, stream,
                       s, lamuda, wsd, out);
}

// Round 2
// 149.414 us; speedup vs baseline: 1.2993x; 1.2993x over previous
//
#include <hip/hip_runtime.h>
#include <math.h>

#define BB 2
#define KK 3
#define NN 2048
#define TA 128          // threads per block in fused kernel (2 waves)
#define CH2 16          // elements/thread in 128-thread phases
#define CHW 32          // elements/lane in wave-local CG (64 lanes * 32 = 2048)
#define CG_IT 30
#define PI_D 3.14159265358979323846
#define TWO_PI_D (2.0 * PI_D)

// ---- workspace layout (doubles) ----
#define WS_NA 0
#define WS_U  8
#define WS_CX (WS_U + BB*NN)
#define WS_CY (WS_CX + BB*KK*NN)
#define WS_TOT (WS_CY + BB*KK*NN)

// ---- output layout (floats) ----
#define OUT_EIF 0
#define OUT_XM  (BB*KK*NN)
#define OUT_YM  (2*BB*KK*NN)
#define OUT_SX  (3*BB*KK*NN)
#define OUT_SY  (3*BB*KK*NN + BB*NN)
#define OUT_LM  (3*BB*KK*NN + 2*BB*NN)
#define OUT_A   (3*BB*KK*NN + 3*BB*NN)
#define OUT_B2  (OUT_A + 1)

// sum across the 64-lane wave (all lanes get the result)
__device__ __forceinline__ double wred(double v) {
    #pragma unroll
    for (int o = 32; o > 0; o >>= 1) v += __shfl_xor(v, o);
    return v;
}

// sum across 128 threads (2 waves) via one LDS handoff
__device__ __forceinline__ double red128(double v, double* sr) {
    v = wred(v);
    const int lane = threadIdx.x & 63, wid = threadIdx.x >> 6;
    __syncthreads();
    if (lane == 0) sr[wid] = v;
    __syncthreads();
    return sr[0] + sr[1];
}

// exclusive prefix over 128 per-thread partial sums
__device__ __forceinline__ double scan128_excl(double run, double* sr) {
    const int lane = threadIdx.x & 63, wid = threadIdx.x >> 6;
    double sc = run;
    #pragma unroll
    for (int o = 1; o < 64; o <<= 1) {
        double v = __shfl_up(sc, o);
        if (lane >= o) sc += v;
    }
    __syncthreads();
    if (lane == 63) sr[wid] = sc;
    __syncthreads();
    double base = (wid == 1) ? sr[0] : 0.0;
    return base + sc - run;
}

// t = c*T^2 p + dg .* p   (T = tridiag(1, -2, 1) with -1 at both end diagonals)
// Fully register-resident; cross-lane boundary values via shfl. No LDS, no barrier.
__device__ __forceinline__ void matvecW(double c, const double (&dgv)[CHW],
                                        const double (&p)[CHW], double (&t)[CHW]) {
    const int lane = threadIdx.x & 63;
    const int gi0 = lane * CHW;
    double pm = __shfl_up(p[CHW-1], 1);
    double pp = __shfl_down(p[0], 1);
    if (gi0 == 0) pm = 0.0;
    if (gi0 + CHW == NN) pp = 0.0;
    // first pass: t = T p  (generic d=-2; end-diagonal fixups after)
    {
        double left = pm;
        #pragma unroll
        for (int j = 0; j < CHW; ++j) {
            double right = (j < CHW-1) ? p[j+1] : pp;
            double v = fma(-2.0, p[j], left) + right;
            left = p[j];
            t[j] = v;
        }
    }
    if (gi0 == 0)        t[0]      += p[0];        // d=-1 at i=0
    if (gi0 + CHW == NN) t[CHW-1]  += p[CHW-1];    // d=-1 at i=N-1
    // second pass: t = c*T t + dg .* p  (rolling overwrite)
    double tm = __shfl_up(t[CHW-1], 1);
    double tp = __shfl_down(t[0], 1);
    if (gi0 == 0) tm = 0.0;
    if (gi0 + CHW == NN) tp = 0.0;
    double t0o = t[0], tLo = t[CHW-1];
    {
        double left = tm;
        #pragma unroll
        for (int j = 0; j < CHW; ++j) {
            double tc = t[j];
            double right = (j < CHW-1) ? t[j+1] : tp;
            double tv = fma(-2.0, tc, left) + right;
            t[j] = fma(c, tv, dgv[j] * p[j]);
            left = tc;
        }
    }
    if (gi0 == 0)        t[0]     += c * t0o;
    if (gi0 + CHW == NN) t[CHW-1] += c * tLo;
}

// wave-local CG for (c*T^2 + diag(dg)) x = b, 30 iters, torch-style early stop.
// b read from LDS (lane-owned contiguous); x0 from global f32 or zero.
__device__ __forceinline__ void cg_wave(double c, const double (&dgv)[CHW],
                                        const double* bbuf, const float* x0g,
                                        double (&x)[CHW]) {
    const int lane = threadIdx.x & 63;
    const int gi0 = lane * CHW;
    double r[CHW], p[CHW], t[CHW];
    #pragma unroll
    for (int j = 0; j < CHW; ++j) {
        x[j] = x0g ? (double)x0g[gi0 + j] : 0.0;
        p[j] = x[j];
    }
    matvecW(c, dgv, p, t);              // t = A x0
    double rs = 0.0;
    #pragma unroll
    for (int j = 0; j < CHW; ++j) {
        r[j] = bbuf[gi0 + j] - t[j];
        p[j] = r[j];
        rs += r[j] * r[j];
    }
    double rsold = wred(rs);
    for (int it = 0; it < CG_IT; ++it) {
        matvecW(c, dgv, p, t);          // t = A p
        double pap = 0.0;
        #pragma unroll
        for (int j = 0; j < CHW; ++j) pap += p[j] * t[j];
        pap = wred(pap);
        double a = rsold / (pap + 1e-12);
        double rs2 = 0.0;
        #pragma unroll
        for (int j = 0; j < CHW; ++j) {
            x[j] += a * p[j];
            r[j] -= a * t[j];
            rs2 += r[j] * r[j];
        }
        double rsnew = wred(rs2);
        if (sqrt(rsnew) < 1e-6) break;  // uniform across wave; matches ref freeze
        double bta = rsnew / (rsold + 1e-12);
        #pragma unroll
        for (int j = 0; j < CHW; ++j) p[j] = r[j] + bta * p[j];
        rsold = rsnew;
    }
}

// ============ fused kernel: one block per (b,k), 2 waves ============
__global__ __launch_bounds__(TA, 1)
void fused_kernel(const float* __restrict__ s, const float* __restrict__ eIF,
                  const float* __restrict__ xm, const float* __restrict__ ym,
                  const float* __restrict__ sum_x, const float* __restrict__ sum_y,
                  const float* __restrict__ lamuda,
                  const float* alpha_p, const float* beta_p,
                  const float* fe_w1, const float* fe_b1,
                  const float* fe_w2, const float* fe_b2,
                  const float* pr_w1, const float* pr_b1,
                  const float* pr_w2, const float* pr_b2,
                  const float* pr_w3, const float* pr_b3,
                  const float* iter_w_p, const int* mode_mask,
                  const float* var_p, const float* fs_p, const int* iter_p,
                  double* __restrict__ wsd, float* __restrict__ out) {
    // raw LDS, aliased:
    //   [0,16K)   shBx f64[2048]: b_x, then solved_x
    //   [16K,32K) shBy f64[2048]: b_y, then solved_y
    //   [32K,40K) csF f32[2048]  \_ aliased by shD f64[2048] = deltaIF, then d_smooth
    //   [40K,48K) snF f32[2048]  /
    __shared__ __align__(16) unsigned char lds_raw[NN*8*2 + NN*8];
    double* shBx = (double*)lds_raw;
    double* shBy = (double*)(lds_raw + NN*8);
    float*  csF  = (float*)(lds_raw + NN*16);
    float*  snF  = (float*)(lds_raw + NN*16 + NN*4);
    double* shD  = (double*)(lds_raw + NN*16);
    __shared__ double sr[2];
    __shared__ double feats[BB*KK][2], inF[BB][2], h1[BB][32], cb[BB][18],
                      r1b[BB][64], r2b[BB][32], resb[BB][2], scal[3];

    const int tid = threadIdx.x;
    const int bk = blockIdx.x;
    const int b = bk / KK;
    const int lane = tid & 63, wid = tid >> 6;
    const int i0 = tid * CH2;

    // ---- phase 0: per-mode diff stats (all modes, duplicated per block) ----
    for (int p = 0; p < BB*KK; ++p) {
        const float* E = eIF + (size_t)p * NN;
        double sm = 0.0, sq = 0.0;
        for (int i = tid; i < NN-1; i += TA) {
            double d = (double)E[i+1] - (double)E[i];
            sm += d; sq += d*d;
        }
        double S = red128(sm, sr);
        double Q = red128(sq, sr);
        if (tid == 0) {
            const double nd = (double)(NN-1);
            double m = S / nd;
            double v = (Q - nd*m*m) / (nd - 1.0);       // ddof=1
            bool mk = mode_mask[p] > 0;
            feats[p][0] = mk ? m : 0.0;
            feats[p][1] = mk ? v : 0.0;
        }
    }
    __syncthreads();

    // ---- phase 1: hyperparameter MLPs (parallel over output neurons) ----
    if (tid < BB*2) {
        int bb = tid >> 1, j = tid & 1;
        double sv = 0.0;
        for (int k = 0; k < KK; ++k) sv += feats[bb*KK+k][j];
        inF[bb][j] = sv / (double)KK;
    }
    __syncthreads();
    if (tid < BB*32) {
        int bb = tid >> 5, o = tid & 31;
        double a = (double)fe_b1[o]
                 + inF[bb][0]*(double)fe_w1[o*2] + inF[bb][1]*(double)fe_w1[o*2+1];
        h1[bb][o] = fmax(a, 0.0);
    }
    __syncthreads();
    if (tid < BB*16) {
        int bb = tid >> 4, o = tid & 15;
        double a = (double)fe_b2[o];
        for (int j = 0; j < 32; ++j) a += h1[bb][j]*(double)fe_w2[o*32+j];
        cb[bb][o] = fmax(a, 0.0);
    }
    if (tid < BB) { cb[tid][16] = (double)alpha_p[0]; cb[tid][17] = (double)beta_p[0]; }
    __syncthreads();
    {   // pr1: exactly 128 outputs
        int bb = tid >> 6, o = tid & 63;
        double a = (double)pr_b1[o];
        for (int j = 0; j < 18; ++j) a += cb[bb][j]*(double)pr_w1[o*18+j];
        r1b[bb][o] = fmax(a, 0.0);
    }
    __syncthreads();
    if (tid < BB*32) {
        int bb = tid >> 5, o = tid & 31;
        double a = (double)pr_b2[o];
        for (int j = 0; j < 64; ++j) a += r1b[bb][j]*(double)pr_w2[o*64+j];
        r2b[bb][o] = fmax(a, 0.0);
    }
    __syncthreads();
    if (tid < BB*2) {
        int bb = tid >> 1, o = tid & 1;
        double a = (double)pr_b3[o];
        for (int j = 0; j < 32; ++j) a += r2b[bb][j]*(double)pr_w3[o*32+j];
        double sg = 1.0 / (1.0 + exp(-(double)iter_w_p[0]*(double)iter_p[0]));
        resb[bb][o] = tanh(a) * sg * 0.1;
    }
    __syncthreads();
    if (tid == 0) {
        double al = (double)alpha_p[0], be = (double)beta_p[0];
        double ma = 0.0, mb = 0.0;
        for (int bb = 0; bb < BB; ++bb) { ma += resb[bb][0]*al; mb += resb[bb][1]*be; }
        ma /= (double)BB; mb /= (double)BB;
        double na = fmin(fmax(al+ma, 1e-6), 0.01);
        double nb = fmin(fmax(be+mb, 1e-6), 0.1);
        float thr32 = (float)pow(10.0, (double)iter_p[0]/36.0 - 10.0);  // ref casts to f32
        double btv = fmin((double)thr32, nb);
        scal[0] = na; scal[1] = nb; scal[2] = btv;
        if (bk == 0) {
            wsd[WS_NA] = na;
            out[OUT_A]  = (float)na;
            out[OUT_B2] = (float)nb;
        }
    }
    __syncthreads();
    const double na = scal[0];
    const double btv = scal[2];
    const double dx = 1.0 / (double)fs_p[0];

    // ---- phase 2: projection u (per-b; registers) ----
    double u_reg[CH2];
    {
        double loc = 0.0;
        #pragma unroll
        for (int j = 0; j < CH2; ++j) {
            int i = i0 + j;
            double d = (double)s[b*NN+i] - (double)sum_x[b*NN+i]
                     - (double)sum_y[b*NN+i] - (double)lamuda[b*NN+i]/na;
            u_reg[j] = d; loc += d*d;
        }
        double nrm2 = red128(loc, sr);
        double var = (double)var_p[0];
        double e = sqrt((double)NN * var);
        double nrm = sqrt(nrm2);
        double scale = (var <= 0.0) ? 0.0 : ((nrm > e) ? e/nrm : 1.0);
        #pragma unroll
        for (int j = 0; j < CH2; ++j) u_reg[j] *= scale;
        if (bk % KK == 0) {     // one block per b exports u for the sum kernel
            #pragma unroll
            for (int j = 0; j < CH2; ++j) wsd[WS_U + (size_t)b*NN + i0 + j] = u_reg[j];
        }
    }

    // ---- phase 3: cumtrapz phase scan + trig + rhs ----
    {
        const float* E = eIF + (size_t)bk * NN;
        double run = 0.0, ph[CH2];
        double eprev = (i0 > 0) ? (double)E[i0-1] : 0.0;
        #pragma unroll
        for (int j = 0; j < CH2; ++j) {
            double ec = (double)E[i0+j];
            double inc = (i0+j == 0) ? 0.0 : 0.5*(eprev+ec)*dx;
            run += inc; ph[j] = run; eprev = ec;
        }
        double excl = scan128_excl(run, sr);
        #pragma unroll
        for (int j = 0; j < CH2; ++j) {
            int i = i0 + j;
            double phase = TWO_PI_D * (excl + ph[j]);
            double sn, cs;
            sincos(phase, &sn, &cs);
            csF[i] = (float)cs; snF[i] = (float)sn;   // staged for CG diagonal only
            double rhs = (double)s[b*NN+i]
                       - ((double)sum_x[b*NN+i] - (double)xm[(size_t)bk*NN+i]*cs)
                       - ((double)sum_y[b*NN+i] - (double)ym[(size_t)bk*NN+i]*sn)
                       - u_reg[j] - (double)lamuda[b*NN+i]/na;
            shBx[i] = cs*rhs; shBy[i] = sn*rhs;       // full-precision b
        }
    }
    __syncthreads();

    // ---- phase 4: CG solves — wave0: x, wave1: y (concurrent, barrier-free) ----
    {
        const double c = 2.0 / na;
        const float*  trg  = wid ? snF : csF;
        const double* bbuf = wid ? shBy : shBx;
        double*       solb = wid ? shBy : shBx;
        const float*  x0g  = (wid ? ym : xm) + (size_t)bk * NN;
        const int gi0 = lane * CHW;
        double dgv[CHW], xsol[CHW];
        #pragma unroll
        for (int j = 0; j < CHW; ++j) { double tr = (double)trg[gi0+j]; dgv[j] = tr*tr + 1e-6; }
        cg_wave(c, dgv, bbuf, x0g, xsol);
        #pragma unroll
        for (int j = 0; j < CHW; ++j) solb[gi0+j] = xsol[j];
    }
    __syncthreads();

    // ---- phase 5: deltaIF (differ5) -> shD ----
    #pragma unroll
    for (int j = 0; j < CH2; ++j) {
        int i = i0 + j;
        double X = shBx[i], Y = shBy[i];
        double xb, yb;
        if (i == 0)          { xb = (shBx[1]-shBx[0])/dx;          yb = (shBy[1]-shBy[0])/dx; }
        else if (i == NN-1)  { xb = (shBx[NN-1]-shBx[NN-2])/dx;    yb = (shBy[NN-1]-shBy[NN-2])/dx; }
        else                 { xb = (shBx[i+1]-shBx[i-1])/(2.0*dx); yb = (shBy[i+1]-shBy[i-1])/(2.0*dx); }
        shD[i] = (X*yb - Y*xb) / ((X*X + Y*Y + 1e-12) * 2.0 * PI_D);
    }
    __syncthreads();

    // ---- phase 6: smoothing CG (wave0 only; wave1 idles at barrier) ----
    if (wid == 0) {
        const double c2 = 2.0 / btv;
        const int gi0 = lane * CHW;
        double dgv[CHW], xsol[CHW];
        #pragma unroll
        for (int j = 0; j < CHW; ++j) dgv[j] = 1.0 + 1e-6;
        cg_wave(c2, dgv, shD, (const float*)nullptr, xsol);
        #pragma unroll
        for (int j = 0; j < CHW; ++j) shD[gi0+j] = xsol[j];
    }
    __syncthreads();

    // ---- phase 7: new phase scan + per-mode outputs ----
    {
        const bool mk = mode_mask[bk] > 0;
        const float* E = eIF + (size_t)bk * NN;
        double run = 0.0, ph[CH2], nev[CH2];
        double eprev = (i0 > 0) ? ((double)E[i0-1] - 0.5*shD[i0-1]) : 0.0;
        #pragma unroll
        for (int j = 0; j < CH2; ++j) {
            int i = i0 + j;
            double ec = (double)E[i] - 0.5*shD[i];
            nev[j] = ec;
            double inc = (i == 0) ? 0.0 : 0.5*(eprev+ec)*dx;
            run += inc; ph[j] = run; eprev = ec;
        }
        double excl = scan128_excl(run, sr);
        #pragma unroll
        for (int j = 0; j < CH2; ++j) {
            int i = i0 + j;
            double nph = TWO_PI_D * (excl + ph[j]);
            double sn, cs;
            sincos(nph, &sn, &cs);
            double cxv = shBx[i] * cs;
            double cyv = shBy[i] * sn;
            out[OUT_EIF + (size_t)bk*NN + i] = mk ? (float)nev[j] : E[i];
            out[OUT_XM  + (size_t)bk*NN + i] = mk ? (float)shBx[i] : xm[(size_t)bk*NN+i];
            out[OUT_YM  + (size_t)bk*NN + i] = mk ? (float)shBy[i] : ym[(size_t)bk*NN+i];
            wsd[WS_CX + (size_t)bk*NN + i] = mk ? cxv : 0.0;
            wsd[WS_CY + (size_t)bk*NN + i] = mk ? cyv : 0.0;
        }
    }
}

// ============ kernel B: k-sum + lamuda (needs all k of a b) ============
__global__ void sum_kernel(const float* __restrict__ s, const float* __restrict__ lamuda,
                           const double* __restrict__ wsd, float* __restrict__ out) {
    const int bidx = blockIdx.x;
    const int i0 = threadIdx.x * CH2;
    const double na = wsd[WS_NA];
    #pragma unroll
    for (int j = 0; j < CH2; ++j) {
        int i = i0 + j;
        double nsx = 0.0, nsy = 0.0;
        #pragma unroll
        for (int k = 0; k < KK; ++k) {
            nsx += wsd[WS_CX + (size_t)(bidx*KK+k)*NN + i];
            nsy += wsd[WS_CY + (size_t)(bidx*KK+k)*NN + i];
        }
        double uu = wsd[WS_U + (size_t)bidx*NN + i];
        out[OUT_SX + bidx*NN + i] = (float)nsx;
        out[OUT_SY + bidx*NN + i] = (float)nsy;
        out[OUT_LM + bidx*NN + i] =
            (float)((double)lamuda[bidx*NN+i] + na*(uu + nsx + nsy - (double)s[bidx*NN+i]));
    }
}

extern "C" void kernel_launch(void* const* d_in, const int* in_sizes, int n_in,
                              void* d_out, int out_size, void* d_ws, size_t ws_size,
                              hipStream_t stream) {
    const float* s      = (const float*)d_in[0];
    const float* eIF    = (const float*)d_in[1];
    const float* xm     = (const float*)d_in[2];
    const float* ym     = (const float*)d_in[3];
    const float* sum_x  = (const float*)d_in[4];
    const float* sum_y  = (const float*)d_in[5];
    const float* lamuda = (const float*)d_in[6];
    const float* alpha  = (const float*)d_in[7];
    const float* beta   = (const float*)d_in[8];
    const float* fe_w1  = (const float*)d_in[9];
    const float* fe_b1  = (const float*)d_in[10];
    const float* fe_w2  = (const float*)d_in[11];
    const float* fe_b2  = (const float*)d_in[12];
    const float* pr_w1  = (const float*)d_in[13];
    const float* pr_b1  = (const float*)d_in[14];
    const float* pr_w2  = (const float*)d_in[15];
    const float* pr_b2  = (const float*)d_in[16];
    const float* pr_w3  = (const float*)d_in[17];
    const float* pr_b3  = (const float*)d_in[18];
    const float* iter_w = (const float*)d_in[19];
    const int*   mode_mask = (const int*)d_in[20];
    const float* var    = (const float*)d_in[21];
    const float* fs     = (const float*)d_in[22];
    const int*   iteration = (const int*)d_in[23];
    float* out = (float*)d_out;
    double* wsd = (double*)d_ws;

    if (ws_size < (size_t)WS_TOT * sizeof(double)) return;   // ~230 KB needed

    hipLaunchKernelGGL(fused_kernel, dim3(BB*KK), dim3(TA), 0, stream,
                       s, eIF, xm, ym, sum_x, sum_y, lamuda, alpha, beta,
                       fe_w1, fe_b1, fe_w2, fe_b2,
                       pr_w1, pr_b1, pr_w2, pr_b2, pr_w3, pr_b3,
                       iter_w, mode_mask, var, fs, iteration, wsd, out);
    hipLaunchKernelGGL(sum_kernel, dim3(BB), dim3(TA), 0, stream,
                       s, lamuda, wsd, out);
}

// Round 3
// 109.655 us; speedup vs baseline: 1.7703x; 1.3626x over previous
//
#include <hip/hip_runtime.h>
#include <math.h>

#define BB 2
#define KK 3
#define NN 2048
#define TA 128          // threads per block in fused kernel (2 waves)
#define CH2 16          // elements/thread in 128-thread phases
#define CHW 32          // elements/lane in wave-local CG (64 lanes * 32 = 2048)
#define CG_IT 30
#define PI_D 3.14159265358979323846
#define TWO_PI_D (2.0 * PI_D)

// ---- workspace layout ----
#define WS_NA 0                      // double scalar
#define WS_U  8                      // doubles, BB*NN
#define WS_F  (WS_U + BB*NN)         // float region starts here (in doubles)
// float region: CX [0, BKN) , CY [BKN, 2*BKN)
#define BKN (BB*KK*NN)

// ---- output layout (floats) ----
#define OUT_EIF 0
#define OUT_XM  (BB*KK*NN)
#define OUT_YM  (2*BB*KK*NN)
#define OUT_SX  (3*BB*KK*NN)
#define OUT_SY  (3*BB*KK*NN + BB*NN)
#define OUT_LM  (3*BB*KK*NN + 2*BB*NN)
#define OUT_A   (3*BB*KK*NN + 3*BB*NN)
#define OUT_B2  (OUT_A + 1)

// fast f64 reciprocal: v_rcp_f64 + 2 Newton steps (~0.5 ulp)
__device__ __forceinline__ double frcp64(double x) {
    double y;
    asm volatile("v_rcp_f64 %0, %1" : "=v"(y) : "v"(x));
    y = fma(y, fma(-x, y, 1.0), y);
    y = fma(y, fma(-x, y, 1.0), y);
    return y;
}

__device__ __forceinline__ double wred(double v) {
    #pragma unroll
    for (int o = 32; o > 0; o >>= 1) v += __shfl_xor(v, o);
    return v;
}
__device__ __forceinline__ float wredf(float v) {
    #pragma unroll
    for (int o = 32; o > 0; o >>= 1) v += __shfl_xor(v, o);
    return v;
}

// sum across 128 threads (2 waves) via one LDS handoff
__device__ __forceinline__ double red128(double v, double* sr) {
    v = wred(v);
    const int lane = threadIdx.x & 63, wid = threadIdx.x >> 6;
    __syncthreads();
    if (lane == 0) sr[wid] = v;
    __syncthreads();
    return sr[0] + sr[1];
}

// exclusive prefix over 128 per-thread partial sums
__device__ __forceinline__ double scan128_excl(double run, double* sr) {
    const int lane = threadIdx.x & 63, wid = threadIdx.x >> 6;
    double sc = run;
    #pragma unroll
    for (int o = 1; o < 64; o <<= 1) {
        double v = __shfl_up(sc, o);
        if (lane >= o) sc += v;
    }
    __syncthreads();
    if (lane == 63) sr[wid] = sc;
    __syncthreads();
    double base = (wid == 1) ? sr[0] : 0.0;
    return base + sc - run;
}

// ======== f32 wave-local matvec: t = c*T^2 p + dg .* p ========
__device__ __forceinline__ void matvecWf(float c, const float (&dgv)[CHW],
                                         const float (&p)[CHW], float (&t)[CHW]) {
    const int lane = threadIdx.x & 63;
    const int gi0 = lane * CHW;
    float pm = __shfl_up(p[CHW-1], 1);
    float pp = __shfl_down(p[0], 1);
    if (gi0 == 0) pm = 0.0f;
    if (gi0 + CHW == NN) pp = 0.0f;
    {
        float left = pm;
        #pragma unroll
        for (int j = 0; j < CHW; ++j) {
            float right = (j < CHW-1) ? p[j+1] : pp;
            float v = fmaf(-2.0f, p[j], left) + right;
            left = p[j]; t[j] = v;
        }
    }
    if (gi0 == 0)        t[0]     += p[0];
    if (gi0 + CHW == NN) t[CHW-1] += p[CHW-1];
    float tm = __shfl_up(t[CHW-1], 1);
    float tp = __shfl_down(t[0], 1);
    if (gi0 == 0) tm = 0.0f;
    if (gi0 + CHW == NN) tp = 0.0f;
    float t0o = t[0], tLo = t[CHW-1];
    {
        float left = tm;
        #pragma unroll
        for (int j = 0; j < CHW; ++j) {
            float tc = t[j];
            float right = (j < CHW-1) ? t[j+1] : tp;
            float tv = fmaf(-2.0f, tc, left) + right;
            t[j] = fmaf(c, tv, dgv[j] * p[j]);
            left = tc;
        }
    }
    if (gi0 == 0)        t[0]     += c * t0o;
    if (gi0 + CHW == NN) t[CHW-1] += c * tLo;
}

// f32 CG, 30 iters, no early-stop (residuals provably never reach 1e-6)
__device__ void cg_wave_f32(float c, const float (&dgv)[CHW], const float* bbuf,
                            const float* x0g, float (&x)[CHW]) {
    const int lane = threadIdx.x & 63;
    const int gi0 = lane * CHW;
    float r[CHW], p[CHW], t[CHW];
    #pragma unroll
    for (int j = 0; j < CHW; ++j) { x[j] = x0g[gi0 + j]; p[j] = x[j]; }
    matvecWf(c, dgv, p, t);
    float rs = 0.0f;
    #pragma unroll
    for (int j = 0; j < CHW; ++j) {
        r[j] = bbuf[gi0 + j] - t[j];
        p[j] = r[j];
        rs = fmaf(r[j], r[j], rs);
    }
    float rsold = wredf(rs);
    for (int it = 0; it < CG_IT; ++it) {
        matvecWf(c, dgv, p, t);
        float pap = 0.0f;
        #pragma unroll
        for (int j = 0; j < CHW; ++j) pap = fmaf(p[j], t[j], pap);
        pap = wredf(pap);
        float a = rsold / (pap + 1e-12f);
        float rs2 = 0.0f;
        #pragma unroll
        for (int j = 0; j < CHW; ++j) {
            x[j] = fmaf(a, p[j], x[j]);
            r[j] = fmaf(-a, t[j], r[j]);
            rs2 = fmaf(r[j], r[j], rs2);
        }
        float rsnew = wredf(rs2);
        float bta = rsnew / (rsold + 1e-12f);
        #pragma unroll
        for (int j = 0; j < CHW; ++j) p[j] = fmaf(bta, p[j], r[j]);
        rsold = rsnew;
    }
}

// ======== f64 wave-local matvec for smoothing: t = c*T^2 p + (1+1e-6) p ========
__device__ __forceinline__ void matvecW64(double c, const double (&p)[CHW], double (&t)[CHW]) {
    const int lane = threadIdx.x & 63;
    const int gi0 = lane * CHW;
    double pm = __shfl_up(p[CHW-1], 1);
    double pp = __shfl_down(p[0], 1);
    if (gi0 == 0) pm = 0.0;
    if (gi0 + CHW == NN) pp = 0.0;
    {
        double left = pm;
        #pragma unroll
        for (int j = 0; j < CHW; ++j) {
            double right = (j < CHW-1) ? p[j+1] : pp;
            double v = fma(-2.0, p[j], left) + right;
            left = p[j]; t[j] = v;
        }
    }
    if (gi0 == 0)        t[0]     += p[0];
    if (gi0 + CHW == NN) t[CHW-1] += p[CHW-1];
    double tm = __shfl_up(t[CHW-1], 1);
    double tp = __shfl_down(t[0], 1);
    if (gi0 == 0) tm = 0.0;
    if (gi0 + CHW == NN) tp = 0.0;
    double t0o = t[0], tLo = t[CHW-1];
    {
        double left = tm;
        #pragma unroll
        for (int j = 0; j < CHW; ++j) {
            double tc = t[j];
            double right = (j < CHW-1) ? t[j+1] : tp;
            double tv = fma(-2.0, tc, left) + right;
            t[j] = fma(c, tv, 1.000001 * p[j]);
            left = tc;
        }
    }
    if (gi0 == 0)        t[0]     += c * t0o;
    if (gi0 + CHW == NN) t[CHW-1] += c * tLo;
}

// f64 smoothing CG, x0 = 0 (so r0 = b, no initial matvec), fast rcp, no early-stop
__device__ void cg_smooth64(double c, const double* bbuf, double (&x)[CHW]) {
    const int lane = threadIdx.x & 63;
    const int gi0 = lane * CHW;
    double r[CHW], p[CHW], t[CHW];
    double rs = 0.0;
    #pragma unroll
    for (int j = 0; j < CHW; ++j) {
        x[j] = 0.0;
        r[j] = bbuf[gi0 + j];
        p[j] = r[j];
        rs = fma(r[j], r[j], rs);
    }
    double rsold = wred(rs);
    for (int it = 0; it < CG_IT; ++it) {
        matvecW64(c, p, t);
        double pap = 0.0;
        #pragma unroll
        for (int j = 0; j < CHW; ++j) pap = fma(p[j], t[j], pap);
        pap = wred(pap);
        double a = rsold * frcp64(pap + 1e-12);
        double rs2 = 0.0;
        #pragma unroll
        for (int j = 0; j < CHW; ++j) {
            x[j] = fma(a, p[j], x[j]);
            r[j] = fma(-a, t[j], r[j]);
            rs2 = fma(r[j], r[j], rs2);
        }
        double rsnew = wred(rs2);
        double bta = rsnew * frcp64(rsold + 1e-12);
        #pragma unroll
        for (int j = 0; j < CHW; ++j) p[j] = fma(bta, p[j], r[j]);
        rsold = rsnew;
    }
}

// ============ fused kernel: one block per (b,k), 2 waves ============
__global__ __launch_bounds__(TA, 1)
void fused_kernel(const float* __restrict__ s, const float* __restrict__ eIF,
                  const float* __restrict__ xm, const float* __restrict__ ym,
                  const float* __restrict__ sum_x, const float* __restrict__ sum_y,
                  const float* __restrict__ lamuda,
                  const float* alpha_p, const float* beta_p,
                  const float* fe_w1, const float* fe_b1,
                  const float* fe_w2, const float* fe_b2,
                  const float* pr_w1, const float* pr_b1,
                  const float* pr_w2, const float* pr_b2,
                  const float* pr_w3, const float* pr_b3,
                  const float* iter_w_p, const int* mode_mask,
                  const float* var_p, const float* fs_p, const int* iter_p,
                  double* __restrict__ wsd, float* __restrict__ out) {
    // LDS, aliased:
    //   [0,8K)    sBx f32[2048]: b_x then solved_x
    //   [8K,16K)  sBy f32[2048]: b_y then solved_y
    //   [16K,24K) csF f32[2048] \_ aliased by shD f64[2048] (deltaIF -> d_smooth)
    //   [24K,32K) snF f32[2048] /
    __shared__ __align__(16) unsigned char lds_raw[NN*16];
    float*  sBx = (float*)lds_raw;
    float*  sBy = sBx + NN;
    float*  csF = sBy + NN;
    float*  snF = csF + NN;
    double* shD = (double*)(lds_raw + NN*8);
    __shared__ double sr[2];
    __shared__ double s12[2][12];
    __shared__ double feats[BB*KK][2], inF[BB][2], h1[BB][32], cb[BB][18],
                      r1b[BB][64], r2b[BB][32], resb[BB][2], scal[3];

    const int tid = threadIdx.x;
    const int bk = blockIdx.x;
    const int b = bk / KK;
    const int lane = tid & 63, wid = tid >> 6;
    const int i0 = tid * CH2;

    // ---- phase 0: per-mode diff stats, 12 dots reduced in ONE interleaved butterfly ----
    {
        double sm[BB*KK], sq[BB*KK];
        #pragma unroll
        for (int m = 0; m < BB*KK; ++m) { sm[m] = 0.0; sq[m] = 0.0; }
        for (int i = tid; i < NN-1; i += TA) {
            #pragma unroll
            for (int m = 0; m < BB*KK; ++m) {
                double d = (double)eIF[(size_t)m*NN + i + 1] - (double)eIF[(size_t)m*NN + i];
                sm[m] += d; sq[m] = fma(d, d, sq[m]);
            }
        }
        #pragma unroll
        for (int o = 32; o > 0; o >>= 1) {
            #pragma unroll
            for (int m = 0; m < BB*KK; ++m) {
                sm[m] += __shfl_xor(sm[m], o);
                sq[m] += __shfl_xor(sq[m], o);
            }
        }
        if (lane == 0) {
            #pragma unroll
            for (int m = 0; m < BB*KK; ++m) { s12[wid][m] = sm[m]; s12[wid][6+m] = sq[m]; }
        }
        __syncthreads();
        if (tid == 0) {
            for (int m = 0; m < BB*KK; ++m) {
                double S = s12[0][m] + s12[1][m];
                double Q = s12[0][6+m] + s12[1][6+m];
                const double nd = (double)(NN-1);
                double mean = S / nd;
                double v = (Q - nd*mean*mean) / (nd - 1.0);   // ddof=1
                bool mk = mode_mask[m] > 0;
                feats[m][0] = mk ? mean : 0.0;
                feats[m][1] = mk ? v : 0.0;
            }
        }
        __syncthreads();
    }

    // ---- phase 1: hyperparameter MLPs ----
    if (tid < BB*2) {
        int bb = tid >> 1, j = tid & 1;
        double sv = 0.0;
        for (int k = 0; k < KK; ++k) sv += feats[bb*KK+k][j];
        inF[bb][j] = sv / (double)KK;
    }
    __syncthreads();
    if (tid < BB*32) {
        int bb = tid >> 5, o = tid & 31;
        double a = (double)fe_b1[o]
                 + inF[bb][0]*(double)fe_w1[o*2] + inF[bb][1]*(double)fe_w1[o*2+1];
        h1[bb][o] = fmax(a, 0.0);
    }
    __syncthreads();
    if (tid < BB*16) {
        int bb = tid >> 4, o = tid & 15;
        double a = (double)fe_b2[o];
        for (int j = 0; j < 32; ++j) a += h1[bb][j]*(double)fe_w2[o*32+j];
        cb[bb][o] = fmax(a, 0.0);
    }
    if (tid < BB) { cb[tid][16] = (double)alpha_p[0]; cb[tid][17] = (double)beta_p[0]; }
    __syncthreads();
    {
        int bb = tid >> 6, o = tid & 63;
        double a = (double)pr_b1[o];
        for (int j = 0; j < 18; ++j) a += cb[bb][j]*(double)pr_w1[o*18+j];
        r1b[bb][o] = fmax(a, 0.0);
    }
    __syncthreads();
    if (tid < BB*32) {
        int bb = tid >> 5, o = tid & 31;
        double a = (double)pr_b2[o];
        for (int j = 0; j < 64; ++j) a += r1b[bb][j]*(double)pr_w2[o*64+j];
        r2b[bb][o] = fmax(a, 0.0);
    }
    __syncthreads();
    if (tid < BB*2) {
        int bb = tid >> 1, o = tid & 1;
        double a = (double)pr_b3[o];
        for (int j = 0; j < 32; ++j) a += r2b[bb][j]*(double)pr_w3[o*32+j];
        double sg = 1.0 / (1.0 + exp(-(double)iter_w_p[0]*(double)iter_p[0]));
        resb[bb][o] = tanh(a) * sg * 0.1;
    }
    __syncthreads();
    if (tid == 0) {
        double al = (double)alpha_p[0], be = (double)beta_p[0];
        double ma = 0.0, mb = 0.0;
        for (int bb = 0; bb < BB; ++bb) { ma += resb[bb][0]*al; mb += resb[bb][1]*be; }
        ma /= (double)BB; mb /= (double)BB;
        double na = fmin(fmax(al+ma, 1e-6), 0.01);
        double nb = fmin(fmax(be+mb, 1e-6), 0.1);
        float thr32 = (float)pow(10.0, (double)iter_p[0]/36.0 - 10.0);  // ref casts to f32
        double btv = fmin((double)thr32, nb);
        scal[0] = na; scal[1] = nb; scal[2] = btv;
        if (bk == 0) {
            wsd[WS_NA] = na;
            out[OUT_A]  = (float)na;
            out[OUT_B2] = (float)nb;
        }
    }
    __syncthreads();
    const double na = scal[0];
    const double btv = scal[2];
    const double inv_na = frcp64(na);
    const double dx = 1.0 / (double)fs_p[0];

    // ---- phase 2: projection u (per-b; registers) ----
    double u_reg[CH2];
    {
        double loc = 0.0;
        #pragma unroll
        for (int j = 0; j < CH2; ++j) {
            int i = i0 + j;
            double d = (double)s[b*NN+i] - (double)sum_x[b*NN+i]
                     - (double)sum_y[b*NN+i] - (double)lamuda[b*NN+i]*inv_na;
            u_reg[j] = d; loc = fma(d, d, loc);
        }
        double nrm2 = red128(loc, sr);
        double var = (double)var_p[0];
        double e = sqrt((double)NN * var);
        double nrm = sqrt(nrm2);
        double scale = (var <= 0.0) ? 0.0 : ((nrm > e) ? e/nrm : 1.0);
        #pragma unroll
        for (int j = 0; j < CH2; ++j) u_reg[j] *= scale;
        if (bk % KK == 0) {
            #pragma unroll
            for (int j = 0; j < CH2; ++j) wsd[WS_U + (size_t)b*NN + i0 + j] = u_reg[j];
        }
    }

    // ---- phase 3: cumtrapz phase scan (f64) + f32 trig + rhs ----
    {
        const float* E = eIF + (size_t)bk * NN;
        double run = 0.0, ph[CH2];
        double eprev = (i0 > 0) ? (double)E[i0-1] : 0.0;
        #pragma unroll
        for (int j = 0; j < CH2; ++j) {
            double ec = (double)E[i0+j];
            double inc = (i0+j == 0) ? 0.0 : 0.5*(eprev+ec)*dx;
            run += inc; ph[j] = run; eprev = ec;
        }
        double excl = scan128_excl(run, sr);
        #pragma unroll
        for (int j = 0; j < CH2; ++j) {
            int i = i0 + j;
            float phase = (float)(TWO_PI_D * (excl + ph[j]));
            float sn, cs;
            sincosf(phase, &sn, &cs);
            csF[i] = cs; snF[i] = sn;
            double rhs = (double)s[b*NN+i]
                       - ((double)sum_x[b*NN+i] - (double)xm[(size_t)bk*NN+i]*(double)cs)
                       - ((double)sum_y[b*NN+i] - (double)ym[(size_t)bk*NN+i]*(double)sn)
                       - u_reg[j] - (double)lamuda[b*NN+i]*inv_na;
            sBx[i] = (float)((double)cs * rhs);
            sBy[i] = (float)((double)sn * rhs);
        }
    }
    __syncthreads();

    // ---- phase 4: f32 CG solves — wave0: x, wave1: y ----
    {
        const float c = (float)(2.0 * inv_na);
        const float* trg = wid ? snF : csF;
        float*       bb  = wid ? sBy : sBx;
        const float* x0g = (wid ? ym : xm) + (size_t)bk * NN;
        const int gi0 = lane * CHW;
        float dgv[CHW], xs[CHW];
        #pragma unroll
        for (int j = 0; j < CHW; ++j) { float tr = trg[gi0+j]; dgv[j] = fmaf(tr, tr, 1e-6f); }
        cg_wave_f32(c, dgv, bb, x0g, xs);
        #pragma unroll
        for (int j = 0; j < CHW; ++j) bb[gi0+j] = xs[j];   // in-place: own range only
    }
    __syncthreads();

    // ---- phase 5: deltaIF (differ5, f64 from f32 solved) -> shD (overwrites trig) ----
    #pragma unroll
    for (int j = 0; j < CH2; ++j) {
        int i = i0 + j;
        double X = (double)sBx[i], Y = (double)sBy[i];
        double xb, yb;
        const double f1 = (double)fs_p[0];        // 1/dx
        const double f2 = 0.5 * f1;               // 1/(2dx)
        if (i == 0)          { xb = ((double)sBx[1]-(double)sBx[0])*f1;       yb = ((double)sBy[1]-(double)sBy[0])*f1; }
        else if (i == NN-1)  { xb = ((double)sBx[NN-1]-(double)sBx[NN-2])*f1; yb = ((double)sBy[NN-1]-(double)sBy[NN-2])*f1; }
        else                 { xb = ((double)sBx[i+1]-(double)sBx[i-1])*f2;   yb = ((double)sBy[i+1]-(double)sBy[i-1])*f2; }
        double den = (fma(X, X, Y*Y) + 1e-12) * TWO_PI_D;
        shD[i] = (X*yb - Y*xb) * frcp64(den);
    }
    __syncthreads();

    // ---- phase 6: f64 smoothing CG (wave0 only) ----
    if (wid == 0) {
        const double c2 = 2.0 * frcp64(btv);
        const int gi0 = lane * CHW;
        double xs[CHW];
        cg_smooth64(c2, shD, xs);
        #pragma unroll
        for (int j = 0; j < CHW; ++j) shD[gi0+j] = xs[j];
    }
    __syncthreads();

    // ---- phase 7: new phase scan + per-mode outputs ----
    {
        const bool mk = mode_mask[bk] > 0;
        const float* E = eIF + (size_t)bk * NN;
        float* wsf = (float*)(wsd + WS_F);
        double run = 0.0, ph[CH2], nev[CH2];
        double eprev = (i0 > 0) ? ((double)E[i0-1] - 0.5*shD[i0-1]) : 0.0;
        #pragma unroll
        for (int j = 0; j < CH2; ++j) {
            int i = i0 + j;
            double ec = (double)E[i] - 0.5*shD[i];
            nev[j] = ec;
            double inc = (i == 0) ? 0.0 : 0.5*(eprev+ec)*dx;
            run += inc; ph[j] = run; eprev = ec;
        }
        double excl = scan128_excl(run, sr);
        #pragma unroll
        for (int j = 0; j < CH2; ++j) {
            int i = i0 + j;
            float nph = (float)(TWO_PI_D * (excl + ph[j]));
            float sn, cs;
            sincosf(nph, &sn, &cs);
            float cxv = sBx[i] * cs;
            float cyv = sBy[i] * sn;
            out[OUT_EIF + (size_t)bk*NN + i] = mk ? (float)nev[j] : E[i];
            out[OUT_XM  + (size_t)bk*NN + i] = mk ? sBx[i] : xm[(size_t)bk*NN+i];
            out[OUT_YM  + (size_t)bk*NN + i] = mk ? sBy[i] : ym[(size_t)bk*NN+i];
            wsf[(size_t)bk*NN + i]       = mk ? cxv : 0.0f;
            wsf[BKN + (size_t)bk*NN + i] = mk ? cyv : 0.0f;
        }
    }
}

// ============ kernel B: k-sum + lamuda (needs all k of a b) ============
__global__ void sum_kernel(const float* __restrict__ s, const float* __restrict__ lamuda,
                           const double* __restrict__ wsd, float* __restrict__ out) {
    const int bidx = blockIdx.x;
    const int i0 = threadIdx.x * CH2;
    const double na = wsd[WS_NA];
    const float* wsf = (const float*)(wsd + WS_F);
    #pragma unroll
    for (int j = 0; j < CH2; ++j) {
        int i = i0 + j;
        double nsx = 0.0, nsy = 0.0;
        #pragma unroll
        for (int k = 0; k < KK; ++k) {
            nsx += (double)wsf[(size_t)(bidx*KK+k)*NN + i];
            nsy += (double)wsf[BKN + (size_t)(bidx*KK+k)*NN + i];
        }
        double uu = wsd[WS_U + (size_t)bidx*NN + i];
        out[OUT_SX + bidx*NN + i] = (float)nsx;
        out[OUT_SY + bidx*NN + i] = (float)nsy;
        out[OUT_LM + bidx*NN + i] =
            (float)((double)lamuda[bidx*NN+i] + na*(uu + nsx + nsy - (double)s[bidx*NN+i]));
    }
}

extern "C" void kernel_launch(void* const* d_in, const int* in_sizes, int n_in,
                              void* d_out, int out_size, void* d_ws, size_t ws_size,
                              hipStream_t stream) {
    const float* s      = (const float*)d_in[0];
    const float* eIF    = (const float*)d_in[1];
    const float* xm     = (const float*)d_in[2];
    const float* ym     = (const float*)d_in[3];
    const float* sum_x  = (const float*)d_in[4];
    const float* sum_y  = (const float*)d_in[5];
    const float* lamuda = (const float*)d_in[6];
    const float* alpha  = (const float*)d_in[7];
    const float* beta   = (const float*)d_in[8];
    const float* fe_w1  = (const float*)d_in[9];
    const float* fe_b1  = (const float*)d_in[10];
    const float* fe_w2  = (const float*)d_in[11];
    const float* fe_b2  = (const float*)d_in[12];
    const float* pr_w1  = (const float*)d_in[13];
    const float* pr_b1  = (const float*)d_in[14];
    const float* pr_w2  = (const float*)d_in[15];
    const float* pr_b2  = (const float*)d_in[16];
    const float* pr_w3  = (const float*)d_in[17];
    const float* pr_b3  = (const float*)d_in[18];
    const float* iter_w = (const float*)d_in[19];
    const int*   mode_mask = (const int*)d_in[20];
    const float* var    = (const float*)d_in[21];
    const float* fs     = (const float*)d_in[22];
    const int*   iteration = (const int*)d_in[23];
    float* out = (float*)d_out;
    double* wsd = (double*)d_ws;

    const size_t need = (size_t)WS_F*8 + (size_t)2*BKN*4;   // ~131 KB
    if (ws_size < need) return;

    hipLaunchKernelGGL(fused_kernel, dim3(BB*KK), dim3(TA), 0, stream,
                       s, eIF, xm, ym, sum_x, sum_y, lamuda, alpha, beta,
                       fe_w1, fe_b1, fe_w2, fe_b2,
                       pr_w1, pr_b1, pr_w2, pr_b2, pr_w3, pr_b3,
                       iter_w, mode_mask, var, fs, iteration, wsd, out);
    hipLaunchKernelGGL(sum_kernel, dim3(BB), dim3(TA), 0, stream,
                       s, lamuda, wsd, out);
}

// Round 4
// 93.931 us; speedup vs baseline: 2.0667x; 1.1674x over previous
//
#include <hip/hip_runtime.h>
#include <math.h>

#define BB 2
#define KK 3
#define NN 2048
#define TA 128          // threads per block in fused kernel (2 waves)
#define CH2 16          // elements/thread in 128-thread phases
#define CHW 32          // elements/lane in wave-local CG (64 lanes * 32 = 2048)
#define CG_IT 30
#define PI_D 3.14159265358979323846
#define TWO_PI_D (2.0 * PI_D)

// ---- workspace layout ----
#define WS_NA 0                      // double scalar
#define WS_U  8                      // doubles, BB*NN
#define WS_F  (WS_U + BB*NN)         // float region starts here (in doubles)
#define BKN (BB*KK*NN)

// ---- output layout (floats) ----
#define OUT_EIF 0
#define OUT_XM  (BB*KK*NN)
#define OUT_YM  (2*BB*KK*NN)
#define OUT_SX  (3*BB*KK*NN)
#define OUT_SY  (3*BB*KK*NN + BB*NN)
#define OUT_LM  (3*BB*KK*NN + 2*BB*NN)
#define OUT_A   (3*BB*KK*NN + 3*BB*NN)
#define OUT_B2  (OUT_A + 1)

// fast f64 reciprocal: v_rcp_f64 + 2 Newton steps
__device__ __forceinline__ double frcp64(double x) {
    double y;
    asm volatile("v_rcp_f64 %0, %1" : "=v"(y) : "v"(x));
    y = fma(y, fma(-x, y, 1.0), y);
    y = fma(y, fma(-x, y, 1.0), y);
    return y;
}

// ======== DPP wave-reduce (all-VALU, no LDS pipe) ========
// row_ror rounds are permutation-direction-proof for sums; bcast15/31 + readlane63
// is the canonical LLVM/rocPRIM wave64 reduce tail.
template<int CTRL>
__device__ __forceinline__ float dadd_f(float v) {
    int t = __builtin_amdgcn_mov_dpp(__float_as_int(v), CTRL, 0xF, 0xF, true);
    return v + __int_as_float(t);
}
__device__ __forceinline__ float wsum_f(float v) {
    v = dadd_f<0x121>(v);   // row_ror:1
    v = dadd_f<0x122>(v);   // row_ror:2
    v = dadd_f<0x124>(v);   // row_ror:4
    v = dadd_f<0x128>(v);   // row_ror:8  -> every lane holds its row-of-16 sum
    v = dadd_f<0x142>(v);   // row_bcast15: lane31=R0+R1, lane63=R2+R3
    v = dadd_f<0x143>(v);   // row_bcast31: lane63=total
    return __int_as_float(__builtin_amdgcn_readlane(__float_as_int(v), 63));
}
template<int CTRL>
__device__ __forceinline__ double dadd_d(double v) {
    int lo = __builtin_amdgcn_mov_dpp(__double2loint(v), CTRL, 0xF, 0xF, true);
    int hi = __builtin_amdgcn_mov_dpp(__double2hiint(v), CTRL, 0xF, 0xF, true);
    return v + __hiloint2double(hi, lo);
}
__device__ __forceinline__ double wsum_d(double v) {
    v = dadd_d<0x121>(v);
    v = dadd_d<0x122>(v);
    v = dadd_d<0x124>(v);
    v = dadd_d<0x128>(v);
    v = dadd_d<0x142>(v);
    v = dadd_d<0x143>(v);
    int lo = __builtin_amdgcn_readlane(__double2loint(v), 63);
    int hi = __builtin_amdgcn_readlane(__double2hiint(v), 63);
    return __hiloint2double(hi, lo);
}

// sum across 128 threads (2 waves) via one LDS handoff
__device__ __forceinline__ double red128(double v, double* sr) {
    v = wsum_d(v);
    const int lane = threadIdx.x & 63, wid = threadIdx.x >> 6;
    __syncthreads();
    if (lane == 0) sr[wid] = v;
    __syncthreads();
    return sr[0] + sr[1];
}

// exclusive prefix over 128 per-thread partial sums
__device__ __forceinline__ double scan128_excl(double run, double* sr) {
    const int lane = threadIdx.x & 63, wid = threadIdx.x >> 6;
    double sc = run;
    #pragma unroll
    for (int o = 1; o < 64; o <<= 1) {
        double v = __shfl_up(sc, o);
        if (lane >= o) sc += v;
    }
    __syncthreads();
    if (lane == 63) sr[wid] = sc;
    __syncthreads();
    double base = (wid == 1) ? sr[0] : 0.0;
    return base + sc - run;
}

// ======== f32 matvec: t = c*T^2 p + dg .* p — ONE boundary shfl round ========
__device__ __forceinline__ void matvecWf(float c, const float (&dgv)[CHW],
                                         const float (&p)[CHW], float (&t)[CHW]) {
    const int lane = threadIdx.x & 63;
    float pm  = __shfl_up(p[CHW-1], 1);
    float pm2 = __shfl_up(p[CHW-2], 1);
    float pp  = __shfl_down(p[0], 1);
    float pp2 = __shfl_down(p[1], 1);
    if (lane == 0)  { pm = 0.0f; pm2 = 0.0f; }
    if (lane == 63) { pp = 0.0f; pp2 = 0.0f; }
    {
        float left = pm;
        #pragma unroll
        for (int j = 0; j < CHW; ++j) {
            float right = (j < CHW-1) ? p[j+1] : pp;
            t[j] = fmaf(-2.0f, p[j], left) + right;
            left = p[j];
        }
    }
    if (lane == 0)  t[0]     += p[0];
    if (lane == 63) t[CHW-1] += p[CHW-1];
    // neighbor t values reconstructed locally (no 2nd shfl round)
    float tm = (lane == 0)  ? 0.0f : fmaf(-2.0f, pm, pm2) + p[0];
    float tp = (lane == 63) ? 0.0f : fmaf(-2.0f, pp, p[CHW-1]) + pp2;
    float t0o = t[0], tLo = t[CHW-1];
    {
        float left = tm;
        #pragma unroll
        for (int j = 0; j < CHW; ++j) {
            float tc = t[j];
            float right = (j < CHW-1) ? t[j+1] : tp;
            float tv = fmaf(-2.0f, tc, left) + right;
            t[j] = fmaf(c, tv, dgv[j] * p[j]);
            left = tc;
        }
    }
    if (lane == 0)  t[0]     += c * t0o;
    if (lane == 63) t[CHW-1] += c * tLo;
}

// ======== Chronopoulos-Gear CG (f32): 1 matvec + 1 joint reduction per iter ====
__device__ void cg_wave_f32(float c, const float (&dgv)[CHW], const float* bbuf,
                            const float* x0g, float (&x)[CHW]) {
    const int lane = threadIdx.x & 63;
    const int gi0 = lane * CHW;
    float r[CHW], p[CHW], sv[CHW], w[CHW];
    #pragma unroll
    for (int j = 0; j < CHW; ++j) x[j] = x0g[gi0 + j];
    matvecWf(c, dgv, x, w);                 // w = A x0
    #pragma unroll
    for (int j = 0; j < CHW; ++j) r[j] = bbuf[gi0 + j] - w[j];
    matvecWf(c, dgv, r, w);                 // w = A r0
    float q0=0,q1=0,q2=0,q3=0, n0=0,n1=0,n2=0,n3=0;
    #pragma unroll
    for (int j = 0; j < CHW; j += 4) {
        q0 = fmaf(r[j],r[j],q0);     q1 = fmaf(r[j+1],r[j+1],q1);
        q2 = fmaf(r[j+2],r[j+2],q2); q3 = fmaf(r[j+3],r[j+3],q3);
        n0 = fmaf(r[j],w[j],n0);     n1 = fmaf(r[j+1],w[j+1],n1);
        n2 = fmaf(r[j+2],w[j+2],n2); n3 = fmaf(r[j+3],w[j+3],n3);
    }
    float rho = wsum_f((q0+q1)+(q2+q3));
    float nu  = wsum_f((n0+n1)+(n2+n3));
    float den = nu + 1e-12f;                // p0 = r0 -> p·Ap = nu
    float alpha = __fdividef(rho, den);
    #pragma unroll
    for (int j = 0; j < CHW; ++j) {
        p[j] = r[j]; sv[j] = w[j];
        x[j] = fmaf(alpha, p[j], x[j]);
        r[j] = fmaf(-alpha, sv[j], r[j]);
    }
    float rho_old = rho, den_old = den;
    for (int it = 1; it < CG_IT; ++it) {
        matvecWf(c, dgv, r, w);             // w = A r
        float a0=0,a1=0,a2=0,a3=0, b0=0,b1=0,b2=0,b3=0;
        #pragma unroll
        for (int j = 0; j < CHW; j += 4) {
            a0 = fmaf(r[j],r[j],a0);     a1 = fmaf(r[j+1],r[j+1],a1);
            a2 = fmaf(r[j+2],r[j+2],a2); a3 = fmaf(r[j+3],r[j+3],a3);
            b0 = fmaf(r[j],w[j],b0);     b1 = fmaf(r[j+1],w[j+1],b1);
            b2 = fmaf(r[j+2],w[j+2],b2); b3 = fmaf(r[j+3],w[j+3],b3);
        }
        float rho_n = wsum_f((a0+a1)+(a2+a3));
        float nu_n  = wsum_f((b0+b1)+(b2+b3));
        float beta = __fdividef(rho_n, rho_old + 1e-12f);
        float dn = fmaf(-beta*beta, den_old, nu_n) + 1e-12f;  // p·Ap recurrence
        float al = __fdividef(rho_n, dn);
        #pragma unroll
        for (int j = 0; j < CHW; ++j) {
            p[j]  = fmaf(beta, p[j], r[j]);
            sv[j] = fmaf(beta, sv[j], w[j]);     // s = A p maintained
            x[j]  = fmaf(al, p[j], x[j]);
            r[j]  = fmaf(-al, sv[j], r[j]);
        }
        rho_old = rho_n; den_old = dn;
    }
}

// ======== f64 matvec for smoothing: t = c*T^2 p + (1+1e-6) p, 1 shfl round ====
__device__ __forceinline__ void matvecW64(double c, const double (&p)[CHW], double (&t)[CHW]) {
    const int lane = threadIdx.x & 63;
    double pm  = __shfl_up(p[CHW-1], 1);
    double pm2 = __shfl_up(p[CHW-2], 1);
    double pp  = __shfl_down(p[0], 1);
    double pp2 = __shfl_down(p[1], 1);
    if (lane == 0)  { pm = 0.0; pm2 = 0.0; }
    if (lane == 63) { pp = 0.0; pp2 = 0.0; }
    {
        double left = pm;
        #pragma unroll
        for (int j = 0; j < CHW; ++j) {
            double right = (j < CHW-1) ? p[j+1] : pp;
            t[j] = fma(-2.0, p[j], left) + right;
            left = p[j];
        }
    }
    if (lane == 0)  t[0]     += p[0];
    if (lane == 63) t[CHW-1] += p[CHW-1];
    double tm = (lane == 0)  ? 0.0 : fma(-2.0, pm, pm2) + p[0];
    double tp = (lane == 63) ? 0.0 : fma(-2.0, pp, p[CHW-1]) + pp2;
    double t0o = t[0], tLo = t[CHW-1];
    {
        double left = tm;
        #pragma unroll
        for (int j = 0; j < CHW; ++j) {
            double tc = t[j];
            double right = (j < CHW-1) ? t[j+1] : tp;
            double tv = fma(-2.0, tc, left) + right;
            t[j] = fma(c, tv, 1.000001 * p[j]);
            left = tc;
        }
    }
    if (lane == 0)  t[0]     += c * t0o;
    if (lane == 63) t[CHW-1] += c * tLo;
}

// f64 standard CG (x0 = 0), DPP reductions, multi-acc dots, fast rcp
__device__ void cg_smooth64(double c, const double* bbuf, double (&x)[CHW]) {
    const int lane = threadIdx.x & 63;
    const int gi0 = lane * CHW;
    double r[CHW], p[CHW], t[CHW];
    double q0=0,q1=0,q2=0,q3=0;
    #pragma unroll
    for (int j = 0; j < CHW; ++j) {
        x[j] = 0.0;
        r[j] = bbuf[gi0 + j];
        p[j] = r[j];
    }
    #pragma unroll
    for (int j = 0; j < CHW; j += 4) {
        q0 = fma(r[j],r[j],q0);     q1 = fma(r[j+1],r[j+1],q1);
        q2 = fma(r[j+2],r[j+2],q2); q3 = fma(r[j+3],r[j+3],q3);
    }
    double rsold = wsum_d((q0+q1)+(q2+q3));
    for (int it = 0; it < CG_IT; ++it) {
        matvecW64(c, p, t);
        double c0=0,c1=0,c2=0,c3=0;
        #pragma unroll
        for (int j = 0; j < CHW; j += 4) {
            c0 = fma(p[j],t[j],c0);     c1 = fma(p[j+1],t[j+1],c1);
            c2 = fma(p[j+2],t[j+2],c2); c3 = fma(p[j+3],t[j+3],c3);
        }
        double pap = wsum_d((c0+c1)+(c2+c3));
        double a = rsold * frcp64(pap + 1e-12);
        double d0=0,d1=0,d2=0,d3=0;
        #pragma unroll
        for (int j = 0; j < CHW; ++j) {
            x[j] = fma(a, p[j], x[j]);
            r[j] = fma(-a, t[j], r[j]);
        }
        #pragma unroll
        for (int j = 0; j < CHW; j += 4) {
            d0 = fma(r[j],r[j],d0);     d1 = fma(r[j+1],r[j+1],d1);
            d2 = fma(r[j+2],r[j+2],d2); d3 = fma(r[j+3],r[j+3],d3);
        }
        double rsnew = wsum_d((d0+d1)+(d2+d3));
        double bta = rsnew * frcp64(rsold + 1e-12);
        #pragma unroll
        for (int j = 0; j < CHW; ++j) p[j] = fma(bta, p[j], r[j]);
        rsold = rsnew;
    }
}

// ============ fused kernel: one block per (b,k), 2 waves ============
__global__ __launch_bounds__(TA, 1)
void fused_kernel(const float* __restrict__ s, const float* __restrict__ eIF,
                  const float* __restrict__ xm, const float* __restrict__ ym,
                  const float* __restrict__ sum_x, const float* __restrict__ sum_y,
                  const float* __restrict__ lamuda,
                  const float* alpha_p, const float* beta_p,
                  const float* fe_w1, const float* fe_b1,
                  const float* fe_w2, const float* fe_b2,
                  const float* pr_w1, const float* pr_b1,
                  const float* pr_w2, const float* pr_b2,
                  const float* pr_w3, const float* pr_b3,
                  const float* iter_w_p, const int* mode_mask,
                  const float* var_p, const float* fs_p, const int* iter_p,
                  double* __restrict__ wsd, float* __restrict__ out) {
    __shared__ __align__(16) unsigned char lds_raw[NN*16];
    float*  sBx = (float*)lds_raw;                    // b_x then solved_x
    float*  sBy = sBx + NN;                           // b_y then solved_y
    float*  csF = sBy + NN;                           // cos  \ aliased by shD (f64)
    float*  snF = csF + NN;                           // sin  /
    double* shD = (double*)(lds_raw + NN*8);          // deltaIF -> d_smooth
    __shared__ double sr[2];
    __shared__ double s12[2][12];
    __shared__ double feats[BB*KK][2], inF[BB][2], h1[BB][32], cb[BB][18],
                      r1b[BB][64], r2b[BB][32], resb[BB][2], scal[3];

    const int tid = threadIdx.x;
    const int bk = blockIdx.x;
    const int b = bk / KK;
    const int lane = tid & 63, wid = tid >> 6;
    const int i0 = tid * CH2;

    // ---- phase 0: per-mode diff stats (12 interleaved DPP reductions) ----
    {
        double sm[BB*KK], sq[BB*KK];
        #pragma unroll
        for (int m = 0; m < BB*KK; ++m) { sm[m] = 0.0; sq[m] = 0.0; }
        for (int i = tid; i < NN-1; i += TA) {
            #pragma unroll
            for (int m = 0; m < BB*KK; ++m) {
                double d = (double)eIF[(size_t)m*NN + i + 1] - (double)eIF[(size_t)m*NN + i];
                sm[m] += d; sq[m] = fma(d, d, sq[m]);
            }
        }
        #pragma unroll
        for (int m = 0; m < BB*KK; ++m) { sm[m] = wsum_d(sm[m]); sq[m] = wsum_d(sq[m]); }
        if (lane == 0) {
            #pragma unroll
            for (int m = 0; m < BB*KK; ++m) { s12[wid][m] = sm[m]; s12[wid][6+m] = sq[m]; }
        }
        __syncthreads();
        if (tid == 0) {
            for (int m = 0; m < BB*KK; ++m) {
                double S = s12[0][m] + s12[1][m];
                double Q = s12[0][6+m] + s12[1][6+m];
                const double nd = (double)(NN-1);
                double mean = S / nd;
                double v = (Q - nd*mean*mean) / (nd - 1.0);   // ddof=1
                bool mk = mode_mask[m] > 0;
                feats[m][0] = mk ? mean : 0.0;
                feats[m][1] = mk ? v : 0.0;
            }
        }
        __syncthreads();
    }

    // ---- phase 1: hyperparameter MLPs ----
    if (tid < BB*2) {
        int bb = tid >> 1, j = tid & 1;
        double sv = 0.0;
        for (int k = 0; k < KK; ++k) sv += feats[bb*KK+k][j];
        inF[bb][j] = sv / (double)KK;
    }
    __syncthreads();
    if (tid < BB*32) {
        int bb = tid >> 5, o = tid & 31;
        double a = (double)fe_b1[o]
                 + inF[bb][0]*(double)fe_w1[o*2] + inF[bb][1]*(double)fe_w1[o*2+1];
        h1[bb][o] = fmax(a, 0.0);
    }
    __syncthreads();
    if (tid < BB*16) {
        int bb = tid >> 4, o = tid & 15;
        double a = (double)fe_b2[o];
        for (int j = 0; j < 32; ++j) a += h1[bb][j]*(double)fe_w2[o*32+j];
        cb[bb][o] = fmax(a, 0.0);
    }
    if (tid < BB) { cb[tid][16] = (double)alpha_p[0]; cb[tid][17] = (double)beta_p[0]; }
    __syncthreads();
    {
        int bb = tid >> 6, o = tid & 63;
        double a = (double)pr_b1[o];
        for (int j = 0; j < 18; ++j) a += cb[bb][j]*(double)pr_w1[o*18+j];
        r1b[bb][o] = fmax(a, 0.0);
    }
    __syncthreads();
    if (tid < BB*32) {
        int bb = tid >> 5, o = tid & 31;
        double a = (double)pr_b2[o];
        for (int j = 0; j < 64; ++j) a += r1b[bb][j]*(double)pr_w2[o*64+j];
        r2b[bb][o] = fmax(a, 0.0);
    }
    __syncthreads();
    if (tid < BB*2) {
        int bb = tid >> 1, o = tid & 1;
        double a = (double)pr_b3[o];
        for (int j = 0; j < 32; ++j) a += r2b[bb][j]*(double)pr_w3[o*32+j];
        double sg = 1.0 / (1.0 + exp(-(double)iter_w_p[0]*(double)iter_p[0]));
        resb[bb][o] = tanh(a) * sg * 0.1;
    }
    __syncthreads();
    if (tid == 0) {
        double al = (double)alpha_p[0], be = (double)beta_p[0];
        double ma = 0.0, mb = 0.0;
        for (int bb = 0; bb < BB; ++bb) { ma += resb[bb][0]*al; mb += resb[bb][1]*be; }
        ma /= (double)BB; mb /= (double)BB;
        double na = fmin(fmax(al+ma, 1e-6), 0.01);
        double nb = fmin(fmax(be+mb, 1e-6), 0.1);
        float thr32 = (float)pow(10.0, (double)iter_p[0]/36.0 - 10.0);  // ref casts to f32
        double btv = fmin((double)thr32, nb);
        scal[0] = na; scal[1] = nb; scal[2] = btv;
        if (bk == 0) {
            wsd[WS_NA] = na;
            out[OUT_A]  = (float)na;
            out[OUT_B2] = (float)nb;
        }
    }
    __syncthreads();
    const double na = scal[0];
    const double btv = scal[2];
    const double inv_na = frcp64(na);
    const double dx = 1.0 / (double)fs_p[0];

    // ---- phase 2: projection u ----
    double u_reg[CH2];
    {
        double loc = 0.0;
        #pragma unroll
        for (int j = 0; j < CH2; ++j) {
            int i = i0 + j;
            double d = (double)s[b*NN+i] - (double)sum_x[b*NN+i]
                     - (double)sum_y[b*NN+i] - (double)lamuda[b*NN+i]*inv_na;
            u_reg[j] = d; loc = fma(d, d, loc);
        }
        double nrm2 = red128(loc, sr);
        double var = (double)var_p[0];
        double e = sqrt((double)NN * var);
        double nrm = sqrt(nrm2);
        double scale = (var <= 0.0) ? 0.0 : ((nrm > e) ? e/nrm : 1.0);
        #pragma unroll
        for (int j = 0; j < CH2; ++j) u_reg[j] *= scale;
        if (bk % KK == 0) {
            #pragma unroll
            for (int j = 0; j < CH2; ++j) wsd[WS_U + (size_t)b*NN + i0 + j] = u_reg[j];
        }
    }

    // ---- phase 3: cumtrapz phase scan (f64) + f32 trig + rhs ----
    {
        const float* E = eIF + (size_t)bk * NN;
        double run = 0.0, ph[CH2];
        double eprev = (i0 > 0) ? (double)E[i0-1] : 0.0;
        #pragma unroll
        for (int j = 0; j < CH2; ++j) {
            double ec = (double)E[i0+j];
            double inc = (i0+j == 0) ? 0.0 : 0.5*(eprev+ec)*dx;
            run += inc; ph[j] = run; eprev = ec;
        }
        double excl = scan128_excl(run, sr);
        #pragma unroll
        for (int j = 0; j < CH2; ++j) {
            int i = i0 + j;
            float phase = (float)(TWO_PI_D * (excl + ph[j]));
            float sn, cs;
            sincosf(phase, &sn, &cs);
            csF[i] = cs; snF[i] = sn;
            double rhs = (double)s[b*NN+i]
                       - ((double)sum_x[b*NN+i] - (double)xm[(size_t)bk*NN+i]*(double)cs)
                       - ((double)sum_y[b*NN+i] - (double)ym[(size_t)bk*NN+i]*(double)sn)
                       - u_reg[j] - (double)lamuda[b*NN+i]*inv_na;
            sBx[i] = (float)((double)cs * rhs);
            sBy[i] = (float)((double)sn * rhs);
        }
    }
    __syncthreads();

    // ---- phase 4: f32 CG-CG solves — wave0: x, wave1: y ----
    {
        const float c = (float)(2.0 * inv_na);
        const float* trg = wid ? snF : csF;
        float*       bb  = wid ? sBy : sBx;
        const float* x0g = (wid ? ym : xm) + (size_t)bk * NN;
        const int gi0 = lane * CHW;
        float dgv[CHW], xs[CHW];
        #pragma unroll
        for (int j = 0; j < CHW; ++j) { float tr = trg[gi0+j]; dgv[j] = fmaf(tr, tr, 1e-6f); }
        cg_wave_f32(c, dgv, bb, x0g, xs);
        #pragma unroll
        for (int j = 0; j < CHW; ++j) bb[gi0+j] = xs[j];   // in-place: own range only
    }
    __syncthreads();

    // ---- phase 5: deltaIF (differ5) -> shD (overwrites trig) ----
    #pragma unroll
    for (int j = 0; j < CH2; ++j) {
        int i = i0 + j;
        double X = (double)sBx[i], Y = (double)sBy[i];
        double xb, yb;
        const double f1 = (double)fs_p[0];
        const double f2 = 0.5 * f1;
        if (i == 0)          { xb = ((double)sBx[1]-(double)sBx[0])*f1;       yb = ((double)sBy[1]-(double)sBy[0])*f1; }
        else if (i == NN-1)  { xb = ((double)sBx[NN-1]-(double)sBx[NN-2])*f1; yb = ((double)sBy[NN-1]-(double)sBy[NN-2])*f1; }
        else                 { xb = ((double)sBx[i+1]-(double)sBx[i-1])*f2;   yb = ((double)sBy[i+1]-(double)sBy[i-1])*f2; }
        double den = (fma(X, X, Y*Y) + 1e-12) * TWO_PI_D;
        shD[i] = (X*yb - Y*xb) * frcp64(den);
    }
    __syncthreads();

    // ---- phase 6: f64 smoothing CG (wave0 only) ----
    if (wid == 0) {
        const double c2 = 2.0 * frcp64(btv);
        const int gi0 = lane * CHW;
        double xs[CHW];
        cg_smooth64(c2, shD, xs);
        #pragma unroll
        for (int j = 0; j < CHW; ++j) shD[gi0+j] = xs[j];
    }
    __syncthreads();

    // ---- phase 7: new phase scan + per-mode outputs ----
    {
        const bool mk = mode_mask[bk] > 0;
        const float* E = eIF + (size_t)bk * NN;
        float* wsf = (float*)(wsd + WS_F);
        double run = 0.0, ph[CH2], nev[CH2];
        double eprev = (i0 > 0) ? ((double)E[i0-1] - 0.5*shD[i0-1]) : 0.0;
        #pragma unroll
        for (int j = 0; j < CH2; ++j) {
            int i = i0 + j;
            double ec = (double)E[i] - 0.5*shD[i];
            nev[j] = ec;
            double inc = (i == 0) ? 0.0 : 0.5*(eprev+ec)*dx;
            run += inc; ph[j] = run; eprev = ec;
        }
        double excl = scan128_excl(run, sr);
        #pragma unroll
        for (int j = 0; j < CH2; ++j) {
            int i = i0 + j;
            float nph = (float)(TWO_PI_D * (excl + ph[j]));
            float sn, cs;
            sincosf(nph, &sn, &cs);
            float cxv = sBx[i] * cs;
            float cyv = sBy[i] * sn;
            out[OUT_EIF + (size_t)bk*NN + i] = mk ? (float)nev[j] : E[i];
            out[OUT_XM  + (size_t)bk*NN + i] = mk ? sBx[i] : xm[(size_t)bk*NN+i];
            out[OUT_YM  + (size_t)bk*NN + i] = mk ? sBy[i] : ym[(size_t)bk*NN+i];
            wsf[(size_t)bk*NN + i]       = mk ? cxv : 0.0f;
            wsf[BKN + (size_t)bk*NN + i] = mk ? cyv : 0.0f;
        }
    }
}

// ============ kernel B: k-sum + lamuda ============
__global__ void sum_kernel(const float* __restrict__ s, const float* __restrict__ lamuda,
                           const double* __restrict__ wsd, float* __restrict__ out) {
    const int bidx = blockIdx.x;
    const int i0 = threadIdx.x * CH2;
    const double na = wsd[WS_NA];
    const float* wsf = (const float*)(wsd + WS_F);
    #pragma unroll
    for (int j = 0; j < CH2; ++j) {
        int i = i0 + j;
        double nsx = 0.0, nsy = 0.0;
        #pragma unroll
        for (int k = 0; k < KK; ++k) {
            nsx += (double)wsf[(size_t)(bidx*KK+k)*NN + i];
            nsy += (double)wsf[BKN + (size_t)(bidx*KK+k)*NN + i];
        }
        double uu = wsd[WS_U + (size_t)bidx*NN + i];
        out[OUT_SX + bidx*NN + i] = (float)nsx;
        out[OUT_SY + bidx*NN + i] = (float)nsy;
        out[OUT_LM + bidx*NN + i] =
            (float)((double)lamuda[bidx*NN+i] + na*(uu + nsx + nsy - (double)s[bidx*NN+i]));
    }
}

extern "C" void kernel_launch(void* const* d_in, const int* in_sizes, int n_in,
                              void* d_out, int out_size, void* d_ws, size_t ws_size,
                              hipStream_t stream) {
    const float* s      = (const float*)d_in[0];
    const float* eIF    = (const float*)d_in[1];
    const float* xm     = (const float*)d_in[2];
    const float* ym     = (const float*)d_in[3];
    const float* sum_x  = (const float*)d_in[4];
    const float* sum_y  = (const float*)d_in[5];
    const float* lamuda = (const float*)d_in[6];
    const float* alpha  = (const float*)d_in[7];
    const float* beta   = (const float*)d_in[8];
    const float* fe_w1  = (const float*)d_in[9];
    const float* fe_b1  = (const float*)d_in[10];
    const float* fe_w2  = (const float*)d_in[11];
    const float* fe_b2  = (const float*)d_in[12];
    const float* pr_w1  = (const float*)d_in[13];
    const float* pr_b1  = (const float*)d_in[14];
    const float* pr_w2  = (const float*)d_in[15];
    const float* pr_b2  = (const float*)d_in[16];
    const float* pr_w3  = (const float*)d_in[17];
    const float* pr_b3  = (const float*)d_in[18];
    const float* iter_w = (const float*)d_in[19];
    const int*   mode_mask = (const int*)d_in[20];
    const float* var    = (const float*)d_in[21];
    const float* fs     = (const float*)d_in[22];
    const int*   iteration = (const int*)d_in[23];
    float* out = (float*)d_out;
    double* wsd = (double*)d_ws;

    const size_t need = (size_t)WS_F*8 + (size_t)2*BKN*4;
    if (ws_size < need) return;

    hipLaunchKernelGGL(fused_kernel, dim3(BB*KK), dim3(TA), 0, stream,
                       s, eIF, xm, ym, sum_x, sum_y, lamuda, alpha, beta,
                       fe_w1, fe_b1, fe_w2, fe_b2,
                       pr_w1, pr_b1, pr_w2, pr_b2, pr_w3, pr_b3,
                       iter_w, mode_mask, var, fs, iteration, wsd, out);
    hipLaunchKernelGGL(sum_kernel, dim3(BB), dim3(TA), 0, stream,
                       s, lamuda, wsd, out);
}